// Round 12
// baseline (334.028 us; speedup 1.0000x reference)
//
#include <hip/hip_runtime.h>

// GIN: 3 layers of {agg = scatter_sum(h[src] -> dst); h = relu(((1+eps)h + agg) @ W + b)}
// then per-graph segment-sum readout (graph_ids sorted) -> 2-layer MLP.
//
// R12: (a) layer re-sharded: block = one 16-node MFMA tile, 4 waves x 4 nodes
//      gather (R9's proven per-wave shape: 1 node per 16-lane group) into
//      block-shared rows[16][64], one barrier, wave wv computes mt=wv of the
//      MFMA epilogue. 25K waves (4x R11) restores R9's occupancy/MLP (R11
//      post-mortem: 6250 waves, 49% occ, 2.42 TB/s vs R9's 3.19).
//      (b) cast+prep_w+bucket_count merged into one dispatch (12->10 launches).
// R10: fused layer + atomic-free two-phase readout. R9: bucketed CSR build.
// R7: f16 H. R5: MFMA bf16 hi/lo 3-product gemm.
// Gather fabric ceiling observed ~3.2 TB/s; FETCH floor ~102MB/layer.

#define SPLIT 16
#define NBLK 512     // edge chunks for bucket build
#define BS 512       // nodes per bucket (pow2)

typedef unsigned short ushort_t;
typedef __bf16 v8bf __attribute__((ext_vector_type(8)));
typedef float v4f __attribute__((ext_vector_type(4)));

__device__ __forceinline__ float h2f_lo(unsigned int v) {
    return (float)__builtin_bit_cast(_Float16, (unsigned short)(v & 0xffffu));
}
__device__ __forceinline__ float h2f_hi(unsigned int v) {
    return (float)__builtin_bit_cast(_Float16, (unsigned short)(v >> 16));
}
__device__ __forceinline__ unsigned int f2h(float f) {
    return (unsigned int)__builtin_bit_cast(unsigned short, (_Float16)f);
}

// Merged: bucket_count (blocks 0..NBLK-1) | cast (next castBlocks) | prep_w (rest)
__global__ __launch_bounds__(256) void pre_kernel(
        const int* __restrict__ dst, int* __restrict__ cnt2d,
        int E, int nbkt, int ebpb,
        const float* __restrict__ x, ushort_t* __restrict__ xh, int n4, int castBlocks,
        const float* __restrict__ W, ushort_t* __restrict__ whi,
        ushort_t* __restrict__ wlo, int wtotal) {
    __shared__ int lcnt[256];
    int t = threadIdx.x;
    int blk = blockIdx.x;
    if (blk < NBLK) {
        lcnt[t] = 0;
        __syncthreads();
        int base = blk * ebpb;
        int end = min(base + ebpb, E);
        for (int i = base + t; i < end; i += 256)
            atomicAdd(&lcnt[dst[i] >> 9], 1);
        __syncthreads();
        if (t < nbkt) cnt2d[(size_t)blk * nbkt + t] = lcnt[t];
    } else if (blk < NBLK + castBlocks) {
        int i = (blk - NBLK) * 256 + t;
        if (i < n4) {
            float4 v = ((const float4*)x)[i];
            uint2 p;
            p.x = f2h(v.x) | (f2h(v.y) << 16);
            p.y = f2h(v.z) | (f2h(v.w) << 16);
            ((uint2*)xh)[i] = p;
        }
    } else {
        int i = (blk - NBLK - castBlocks) * 256 + t;
        if (i < wtotal) {
            int l = i >> 12, r = i & 4095;
            int n = r >> 6, k = r & 63;
            float w = W[l * 4096 + k * 64 + n];
            __bf16 h = (__bf16)w;
            float rem = w - (float)h;
            whi[i] = __builtin_bit_cast(ushort_t, h);
            wlo[i] = __builtin_bit_cast(ushort_t, (__bf16)rem);
        }
    }
}

// B1: block b scans column b of cnt2d over NBLK chunks -> blkoff[b][blk], btot[b]
__global__ __launch_bounds__(256) void colscan_kernel(
        const int* __restrict__ cnt2d, int* __restrict__ blkoff,
        int* __restrict__ btot, int nbkt) {
    __shared__ int sh[256];
    int b = blockIdx.x, t = threadIdx.x;
    int i0 = 2 * t, i1 = 2 * t + 1;
    int v0 = cnt2d[(size_t)i0 * nbkt + b];
    int v1 = cnt2d[(size_t)i1 * nbkt + b];
    int pair = v0 + v1;
    sh[t] = pair;
    __syncthreads();
    for (int off = 1; off < 256; off <<= 1) {
        int u = (t >= off) ? sh[t - off] : 0;
        __syncthreads();
        sh[t] += u;
        __syncthreads();
    }
    int ex = sh[t] - pair;
    blkoff[(size_t)b * NBLK + i0] = ex;
    blkoff[(size_t)b * NBLK + i1] = ex + v0;
    if (t == 255) btot[b] = sh[255];
}

// B2: scan btot[nbkt] -> bbase[nbkt+1]; offsets[N]=E.
__global__ __launch_bounds__(256) void bucket_base_kernel(
        const int* __restrict__ btot, int* __restrict__ bbase,
        int* __restrict__ offsets, int nbkt, int N, int E) {
    __shared__ int sh[256];
    int t = threadIdx.x;
    int v = (t < nbkt) ? btot[t] : 0;
    sh[t] = v;
    __syncthreads();
    for (int off = 1; off < 256; off <<= 1) {
        int u = (t >= off) ? sh[t - off] : 0;
        __syncthreads();
        sh[t] += u;
        __syncthreads();
    }
    if (t < nbkt) bbase[t] = sh[t] - v;
    if (t == 0) { bbase[nbkt] = E; offsets[N] = E; }
}

// C: scatter edges into bucket regions as packed (src<<9)|d_local.
__global__ __launch_bounds__(256) void bucket_scatter_kernel(
        const int* __restrict__ src, const int* __restrict__ dst,
        const int* __restrict__ bbase, const int* __restrict__ blkoff,
        unsigned int* __restrict__ bkt, int E, int nbkt, int ebpb) {
    __shared__ int lbase[256];
    __shared__ int lrank[256];
    int t = threadIdx.x;
    if (t < nbkt) lbase[t] = bbase[t] + blkoff[(size_t)t * NBLK + blockIdx.x];
    lrank[t] = 0;
    __syncthreads();
    int base = blockIdx.x * ebpb;
    int end = min(base + ebpb, E);
    for (int i = base + t; i < end; i += 256) {
        int d = dst[i];
        int b = d >> 9;
        int r = atomicAdd(&lrank[b], 1);
        bkt[lbase[b] + r] = ((unsigned int)src[i] << 9) | (unsigned int)(d & (BS - 1));
    }
}

// D: block b = bucket b. LDS hist + scan -> offsets + csr (LDS atomics only).
__global__ __launch_bounds__(256) void csr_build_kernel(
        const unsigned int* __restrict__ bkt, const int* __restrict__ bbase,
        int* __restrict__ offsets, int* __restrict__ csr, int N, int nbkt) {
    __shared__ int cnt[BS];
    __shared__ int rank[BS];
    __shared__ int sh[256];
    int b = blockIdx.x, t = threadIdx.x;
    cnt[t] = 0; cnt[t + 256] = 0;
    rank[t] = 0; rank[t + 256] = 0;
    __syncthreads();
    int base = bbase[b], end = bbase[b + 1];
    for (int i = base + t; i < end; i += 256)
        atomicAdd(&cnt[bkt[i] & (BS - 1)], 1);
    __syncthreads();
    int i0 = 2 * t, i1 = 2 * t + 1;
    int v0 = cnt[i0], v1 = cnt[i1];
    int pair = v0 + v1;
    sh[t] = pair;
    __syncthreads();
    for (int off = 1; off < 256; off <<= 1) {
        int u = (t >= off) ? sh[t - off] : 0;
        __syncthreads();
        sh[t] += u;
        __syncthreads();
    }
    int ex = sh[t] - pair;
    __syncthreads();
    cnt[i0] = ex;
    cnt[i1] = ex + v0;
    __syncthreads();
    int d0 = (b << 9) + i0;
    if (d0 <= N) offsets[d0] = base + cnt[i0];
    int d1 = (b << 9) + i1;
    if (d1 <= N) offsets[d1] = base + cnt[i1];
    for (int i = base + t; i < end; i += 256) {
        unsigned int v = bkt[i];
        int dl = v & (BS - 1);
        int r = atomicAdd(&rank[dl], 1);
        csr[base + cnt[dl] + r] = (int)(v >> 9);
    }
}

// Fused GIN layer, R12: block = one 16-node tile, 4 waves.
// Gather: wave wv owns nodes wv*4..wv*4+3 (one per 16-lane group, R9 shape),
// preload 32 idx, unroll-8 shfl+row-load -> block-shared rows[16][64].
// One barrier. Epilogue: wave wv computes output-dim tile mt=wv (6 MFMAs).
__global__ __launch_bounds__(256) void layer_kernel(
        const ushort_t* __restrict__ hin, ushort_t* __restrict__ hout,
        const int* __restrict__ offsets, const int* __restrict__ csr,
        const ushort_t* __restrict__ wt_hi, const ushort_t* __restrict__ wt_lo,
        const float* __restrict__ gin_b, const float* __restrict__ eps_arr,
        int layer, int N) {
    __shared__ float rows[16 * 64];       // 4KB: 16 nodes x 64 dims
    int t = threadIdx.x;
    int wv = t >> 6, lane = t & 63;
    int tile = blockIdx.x;
    float eps1 = 1.0f + eps_arr[layer];

    int nq = lane >> 4;        // group 0..3
    int sl = lane & 15;        // uint2 slot (dims 4sl..4sl+3)
    int gbase = lane & 48;     // group's first lane

    int node = tile * 16 + wv * 4 + nq;   // this wave's node for this group
    float ax = 0.f, ay = 0.f, az = 0.f, aw = 0.f;
    if (node < N) {
        int a = offsets[node], b = offsets[node + 1];
        int deg = b - a;
        int idxA = (sl < deg) ? csr[a + sl] : 0;
        int idxB = (16 + sl < deg) ? csr[a + 16 + sl] : 0;
        int d1 = min(deg, 16);
        #pragma unroll 8
        for (int j = 0; j < d1; ++j) {
            int s = __shfl(idxA, gbase + j, 64);
            uint2 v = ((const uint2*)(hin + (size_t)s * 64))[sl];
            ax += h2f_lo(v.x); ay += h2f_hi(v.x);
            az += h2f_lo(v.y); aw += h2f_hi(v.y);
        }
        int d2 = min(deg, 32);
        #pragma unroll 8
        for (int j = 16; j < d2; ++j) {
            int s = __shfl(idxB, gbase + (j - 16), 64);
            uint2 v = ((const uint2*)(hin + (size_t)s * 64))[sl];
            ax += h2f_lo(v.x); ay += h2f_hi(v.x);
            az += h2f_lo(v.y); aw += h2f_hi(v.y);
        }
        for (int e = a + 32; e < b; ++e) {    // rare: deg > 32
            int s = csr[e];
            uint2 v = ((const uint2*)(hin + (size_t)s * 64))[sl];
            ax += h2f_lo(v.x); ay += h2f_hi(v.x);
            az += h2f_lo(v.y); aw += h2f_hi(v.y);
        }
        uint2 self = ((const uint2*)(hin + (size_t)node * 64))[sl];
        ax = fmaf(eps1, h2f_lo(self.x), ax);
        ay = fmaf(eps1, h2f_hi(self.x), ay);
        az = fmaf(eps1, h2f_lo(self.y), az);
        aw = fmaf(eps1, h2f_hi(self.y), aw);
    }
    float4 r4; r4.x = ax; r4.y = ay; r4.z = az; r4.w = aw;
    *(float4*)&rows[(wv * 4 + nq) * 64 + sl * 4] = r4;
    __syncthreads();

    // epilogue: wave wv = output-dim tile mt
    int c = lane & 15;     // node within tile / n-index
    int q = lane >> 4;     // quad
    int node16 = tile * 16 + c;
    int mt = wv;

    const ushort_t* Whi = wt_hi + layer * 4096;
    const ushort_t* Wlo = wt_lo + layer * 4096;
    const float*    bl  = gin_b + layer * 64;

    v8bf bhi[2], blo2[2];
    #pragma unroll
    for (int kt = 0; kt < 2; ++kt) {
        float4 f0 = *(float4*)&rows[c * 64 + kt * 32 + q * 8];
        float4 f1 = *(float4*)&rows[c * 64 + kt * 32 + q * 8 + 4];
        float xs[8] = {f0.x, f0.y, f0.z, f0.w, f1.x, f1.y, f1.z, f1.w};
        #pragma unroll
        for (int j = 0; j < 8; ++j) {
            __bf16 h = (__bf16)xs[j];
            bhi[kt][j] = h;
            blo2[kt][j] = (__bf16)(xs[j] - (float)h);
        }
    }

    v4f acc = {0.f, 0.f, 0.f, 0.f};
    #pragma unroll
    for (int kt = 0; kt < 2; ++kt) {
        int dim = mt * 16 + c;
        size_t off = (size_t)dim * 64 + kt * 32 + q * 8;
        v8bf ah = __builtin_bit_cast(v8bf, *(const uint4*)(Whi + off));
        v8bf al = __builtin_bit_cast(v8bf, *(const uint4*)(Wlo + off));
        acc = __builtin_amdgcn_mfma_f32_16x16x32_bf16(ah, bhi[kt],  acc, 0, 0, 0);
        acc = __builtin_amdgcn_mfma_f32_16x16x32_bf16(ah, blo2[kt], acc, 0, 0, 0);
        acc = __builtin_amdgcn_mfma_f32_16x16x32_bf16(al, bhi[kt],  acc, 0, 0, 0);
    }
    float4 bv = ((const float4*)(bl + mt * 16))[q];
    float o0 = fmaxf(acc[0] + bv.x, 0.f);
    float o1 = fmaxf(acc[1] + bv.y, 0.f);
    float o2 = fmaxf(acc[2] + bv.z, 0.f);
    float o3 = fmaxf(acc[3] + bv.w, 0.f);
    uint2 pk;
    pk.x = f2h(o0) | (f2h(o1) << 16);
    pk.y = f2h(o2) | (f2h(o3) << 16);
    if (node16 < N)
        *(uint2*)(hout + (size_t)node16 * 64 + mt * 16 + q * 4) = pk;
}

// Phase 1: dense partials, no atomics. gpart[(graph*SPLIT+sp)*192 + t].
__global__ __launch_bounds__(192) void readout_part_kernel(
        const ushort_t* __restrict__ H, const int* __restrict__ gids,
        float* __restrict__ gpart, int N) {
    int graph = blockIdx.x / SPLIT;
    int sp    = blockIdx.x % SPLIT;
    int lo = 0, hi = N;
    while (lo < hi) { int mid = (lo + hi) >> 1; if (gids[mid] < graph) lo = mid + 1; else hi = mid; }
    int start = lo;
    int lo2 = start, hi2 = N;
    while (lo2 < hi2) { int mid = (lo2 + hi2) >> 1; if (gids[mid] < graph + 1) lo2 = mid + 1; else hi2 = mid; }
    int end = lo2;
    int t = threadIdx.x;            // 0..191
    int l = t >> 6, d = t & 63;
    float acc = 0.0f;
    int cnt = end - start;
    if (cnt > 0) {
        int per = (cnt + SPLIT - 1) / SPLIT;
        int cs = start + sp * per;
        int ce = min(cs + per, end);
        const ushort_t* Hl = H + (size_t)l * N * 64;
        for (int n = cs; n < ce; ++n)
            acc += (float)__builtin_bit_cast(_Float16, Hl[(size_t)n * 64 + d]);
    }
    gpart[(size_t)(graph * SPLIT + sp) * 192 + t] = acc;   // unconditional
}

// Phase 2 fused with MLP: sum 16 partials -> gr, then 2-layer MLP.
__global__ __launch_bounds__(192) void mlp_kernel(
        const float* __restrict__ gpart,
        const float* __restrict__ W1, const float* __restrict__ b1,
        const float* __restrict__ W2, const float* __restrict__ b2,
        float* __restrict__ out) {
    __shared__ float gr[192];
    __shared__ float hid[128];
    int graph = blockIdx.x;
    int t = threadIdx.x;
    float a = 0.f;
    #pragma unroll
    for (int sp = 0; sp < SPLIT; ++sp)
        a += gpart[(size_t)(graph * SPLIT + sp) * 192 + t];
    gr[t] = a;
    __syncthreads();
    if (t < 128) {
        float s = b1[t];
        for (int k = 0; k < 192; ++k) s = fmaf(gr[k], W1[k * 128 + t], s);
        hid[t] = fmaxf(s, 0.0f);
    }
    __syncthreads();
    if (t < 32) {
        float s = b2[t];
        for (int k = 0; k < 128; ++k) s = fmaf(hid[k], W2[k * 32 + t], s);
        out[graph * 32 + t] = s;
    }
}

extern "C" void kernel_launch(void* const* d_in, const int* in_sizes, int n_in,
                              void* d_out, int out_size, void* d_ws, size_t ws_size,
                              hipStream_t stream) {
    const float* x     = (const float*)d_in[0];
    const float* gin_W = (const float*)d_in[1];
    const float* gin_b = (const float*)d_in[2];
    const float* eps   = (const float*)d_in[3];
    const float* r_W1  = (const float*)d_in[4];
    const float* r_b1  = (const float*)d_in[5];
    const float* r_W2  = (const float*)d_in[6];
    const float* r_b2  = (const float*)d_in[7];
    const int*   src   = (const int*)d_in[8];
    const int*   dst   = (const int*)d_in[9];
    const int*   gids  = (const int*)d_in[10];

    int N = in_sizes[0] / 64;       // 100000
    int E = in_sizes[8];            // 1200000
    int B = out_size / 32;          // 256

    int nbkt = (N + BS - 1) / BS;   // 196 (<= 256)
    int ebpb = (E + NBLK - 1) / NBLK;
    int n4 = N * 64 / 4;
    int castBlocks = (n4 + 255) / 256;
    int wtotal = 3 * 4096;
    int prepBlocks = (wtotal + 255) / 256;

    // workspace layout (4B words), all regions fully written before read:
    //   gpart[B*SPLIT*192]
    //   cnt2d[NBLK*nbkt] | blkoff[nbkt*NBLK] | btot[nbkt] | bbase[nbkt+1]
    //   offsets[N+1] | bkt[E] | csr[E] | pad
    //   xh[N*64 f16] | H[3*N*64 f16] | whi[3*4096] | wlo[3*4096]
    int* ws       = (int*)d_ws;
    float* gpart  = (float*)ws;
    int* cnt2d    = ws + (size_t)B * SPLIT * 192;
    int* blkoff   = cnt2d + (size_t)NBLK * nbkt;
    int* btot     = blkoff + (size_t)nbkt * NBLK;
    int* bbase    = btot + nbkt;
    int* offsets  = bbase + (nbkt + 1);
    unsigned int* bkt = (unsigned int*)(offsets + (N + 1));
    int* csr      = (int*)(bkt + E);
    size_t w      = (size_t)(csr + E - ws);
    w = (w + 15) & ~(size_t)15;     // 64B align
    ushort_t* xh  = (ushort_t*)(ws + w);
    ushort_t* H   = xh + (size_t)N * 64;
    ushort_t* whi = H + 3 * (size_t)N * 64;
    ushort_t* wlo = whi + 3 * 4096;

    pre_kernel<<<NBLK + castBlocks + prepBlocks, 256, 0, stream>>>(
        dst, cnt2d, E, nbkt, ebpb, x, xh, n4, castBlocks, gin_W, whi, wlo, wtotal);
    colscan_kernel<<<nbkt, 256, 0, stream>>>(cnt2d, blkoff, btot, nbkt);
    bucket_base_kernel<<<1, 256, 0, stream>>>(btot, bbase, offsets, nbkt, N, E);
    bucket_scatter_kernel<<<NBLK, 256, 0, stream>>>(src, dst, bbase, blkoff, bkt, E, nbkt, ebpb);
    csr_build_kernel<<<nbkt, 256, 0, stream>>>(bkt, bbase, offsets, csr, N, nbkt);

    int lbk = (N + 15) / 16;        // one 16-node tile per block, 4 waves
    ushort_t* H0 = H;
    ushort_t* H1 = H + (size_t)N * 64;
    ushort_t* H2 = H + 2 * (size_t)N * 64;

    layer_kernel<<<lbk, 256, 0, stream>>>(xh, H0, offsets, csr, whi, wlo, gin_b, eps, 0, N);
    layer_kernel<<<lbk, 256, 0, stream>>>(H0, H1, offsets, csr, whi, wlo, gin_b, eps, 1, N);
    layer_kernel<<<lbk, 256, 0, stream>>>(H1, H2, offsets, csr, whi, wlo, gin_b, eps, 2, N);

    readout_part_kernel<<<B * SPLIT, 192, 0, stream>>>(H, gids, gpart, N);
    mlp_kernel<<<B, 192, 0, stream>>>(gpart, r_W1, r_b1, r_W2, r_b2, (float*)d_out);
}

// Round 13
// 323.268 us; speedup vs baseline: 1.0333x; 1.0333x over previous
//
#include <hip/hip_runtime.h>

// GIN: 3 layers of {agg = scatter_sum(h[src] -> dst); h = relu(((1+eps)h + agg) @ W + b)}
// then per-graph segment-sum readout (graph_ids sorted) -> 2-layer MLP.
//
// R13: uniform-trip gather. Rate comparison across R9-R12 showed the winner
//      (R9, 2.58 TB/s read) splits ONE node's edges across all 4 lane-groups
//      (trip = deg/4, wave-uniform); R10-12 (2.0-2.2 TB/s) gave each group a
//      different node -> wave loop runs max(4 Poisson-12 degs) ~ 1.37x waste.
//      Layer now gathers its 16 nodes sequentially in R9 shape (one offsets
//      load shfl-shared, idx prefetch pipeline, shfl_xor reduce), keeping
//      R10's wave-autonomous tile + MFMA epilogue (no barrier).
// R12: merged pre. R10: fused layer + atomic-free readout. R9: bucketed CSR.
// R7: f16 H. R5: MFMA bf16 hi/lo 3-product gemm.

#define SPLIT 16
#define NBLK 512     // edge chunks for bucket build
#define BS 512       // nodes per bucket (pow2)

typedef unsigned short ushort_t;
typedef __bf16 v8bf __attribute__((ext_vector_type(8)));
typedef float v4f __attribute__((ext_vector_type(4)));

__device__ __forceinline__ float h2f_lo(unsigned int v) {
    return (float)__builtin_bit_cast(_Float16, (unsigned short)(v & 0xffffu));
}
__device__ __forceinline__ float h2f_hi(unsigned int v) {
    return (float)__builtin_bit_cast(_Float16, (unsigned short)(v >> 16));
}
__device__ __forceinline__ unsigned int f2h(float f) {
    return (unsigned int)__builtin_bit_cast(unsigned short, (_Float16)f);
}

// Merged: bucket_count (blocks 0..NBLK-1) | cast (next castBlocks) | prep_w (rest)
__global__ __launch_bounds__(256) void pre_kernel(
        const int* __restrict__ dst, int* __restrict__ cnt2d,
        int E, int nbkt, int ebpb,
        const float* __restrict__ x, ushort_t* __restrict__ xh, int n4, int castBlocks,
        const float* __restrict__ W, ushort_t* __restrict__ whi,
        ushort_t* __restrict__ wlo, int wtotal) {
    __shared__ int lcnt[256];
    int t = threadIdx.x;
    int blk = blockIdx.x;
    if (blk < NBLK) {
        lcnt[t] = 0;
        __syncthreads();
        int base = blk * ebpb;
        int end = min(base + ebpb, E);
        for (int i = base + t; i < end; i += 256)
            atomicAdd(&lcnt[dst[i] >> 9], 1);
        __syncthreads();
        if (t < nbkt) cnt2d[(size_t)blk * nbkt + t] = lcnt[t];
    } else if (blk < NBLK + castBlocks) {
        int i = (blk - NBLK) * 256 + t;
        if (i < n4) {
            float4 v = ((const float4*)x)[i];
            uint2 p;
            p.x = f2h(v.x) | (f2h(v.y) << 16);
            p.y = f2h(v.z) | (f2h(v.w) << 16);
            ((uint2*)xh)[i] = p;
        }
    } else {
        int i = (blk - NBLK - castBlocks) * 256 + t;
        if (i < wtotal) {
            int l = i >> 12, r = i & 4095;
            int n = r >> 6, k = r & 63;
            float w = W[l * 4096 + k * 64 + n];
            __bf16 h = (__bf16)w;
            float rem = w - (float)h;
            whi[i] = __builtin_bit_cast(ushort_t, h);
            wlo[i] = __builtin_bit_cast(ushort_t, (__bf16)rem);
        }
    }
}

// B1: block b scans column b of cnt2d over NBLK chunks -> blkoff[b][blk], btot[b]
__global__ __launch_bounds__(256) void colscan_kernel(
        const int* __restrict__ cnt2d, int* __restrict__ blkoff,
        int* __restrict__ btot, int nbkt) {
    __shared__ int sh[256];
    int b = blockIdx.x, t = threadIdx.x;
    int i0 = 2 * t, i1 = 2 * t + 1;
    int v0 = cnt2d[(size_t)i0 * nbkt + b];
    int v1 = cnt2d[(size_t)i1 * nbkt + b];
    int pair = v0 + v1;
    sh[t] = pair;
    __syncthreads();
    for (int off = 1; off < 256; off <<= 1) {
        int u = (t >= off) ? sh[t - off] : 0;
        __syncthreads();
        sh[t] += u;
        __syncthreads();
    }
    int ex = sh[t] - pair;
    blkoff[(size_t)b * NBLK + i0] = ex;
    blkoff[(size_t)b * NBLK + i1] = ex + v0;
    if (t == 255) btot[b] = sh[255];
}

// B2: scan btot[nbkt] -> bbase[nbkt+1]; offsets[N]=E.
__global__ __launch_bounds__(256) void bucket_base_kernel(
        const int* __restrict__ btot, int* __restrict__ bbase,
        int* __restrict__ offsets, int nbkt, int N, int E) {
    __shared__ int sh[256];
    int t = threadIdx.x;
    int v = (t < nbkt) ? btot[t] : 0;
    sh[t] = v;
    __syncthreads();
    for (int off = 1; off < 256; off <<= 1) {
        int u = (t >= off) ? sh[t - off] : 0;
        __syncthreads();
        sh[t] += u;
        __syncthreads();
    }
    if (t < nbkt) bbase[t] = sh[t] - v;
    if (t == 0) { bbase[nbkt] = E; offsets[N] = E; }
}

// C: scatter edges into bucket regions as packed (src<<9)|d_local.
__global__ __launch_bounds__(256) void bucket_scatter_kernel(
        const int* __restrict__ src, const int* __restrict__ dst,
        const int* __restrict__ bbase, const int* __restrict__ blkoff,
        unsigned int* __restrict__ bkt, int E, int nbkt, int ebpb) {
    __shared__ int lbase[256];
    __shared__ int lrank[256];
    int t = threadIdx.x;
    if (t < nbkt) lbase[t] = bbase[t] + blkoff[(size_t)t * NBLK + blockIdx.x];
    lrank[t] = 0;
    __syncthreads();
    int base = blockIdx.x * ebpb;
    int end = min(base + ebpb, E);
    for (int i = base + t; i < end; i += 256) {
        int d = dst[i];
        int b = d >> 9;
        int r = atomicAdd(&lrank[b], 1);
        bkt[lbase[b] + r] = ((unsigned int)src[i] << 9) | (unsigned int)(d & (BS - 1));
    }
}

// D: block b = bucket b. LDS hist + scan -> offsets + csr (LDS atomics only).
__global__ __launch_bounds__(256) void csr_build_kernel(
        const unsigned int* __restrict__ bkt, const int* __restrict__ bbase,
        int* __restrict__ offsets, int* __restrict__ csr, int N, int nbkt) {
    __shared__ int cnt[BS];
    __shared__ int rank[BS];
    __shared__ int sh[256];
    int b = blockIdx.x, t = threadIdx.x;
    cnt[t] = 0; cnt[t + 256] = 0;
    rank[t] = 0; rank[t + 256] = 0;
    __syncthreads();
    int base = bbase[b], end = bbase[b + 1];
    for (int i = base + t; i < end; i += 256)
        atomicAdd(&cnt[bkt[i] & (BS - 1)], 1);
    __syncthreads();
    int i0 = 2 * t, i1 = 2 * t + 1;
    int v0 = cnt[i0], v1 = cnt[i1];
    int pair = v0 + v1;
    sh[t] = pair;
    __syncthreads();
    for (int off = 1; off < 256; off <<= 1) {
        int u = (t >= off) ? sh[t - off] : 0;
        __syncthreads();
        sh[t] += u;
        __syncthreads();
    }
    int ex = sh[t] - pair;
    __syncthreads();
    cnt[i0] = ex;
    cnt[i1] = ex + v0;
    __syncthreads();
    int d0 = (b << 9) + i0;
    if (d0 <= N) offsets[d0] = base + cnt[i0];
    int d1 = (b << 9) + i1;
    if (d1 <= N) offsets[d1] = base + cnt[i1];
    for (int i = base + t; i < end; i += 256) {
        unsigned int v = bkt[i];
        int dl = v & (BS - 1);
        int r = atomicAdd(&rank[dl], 1);
        csr[base + cnt[dl] + r] = (int)(v >> 9);
    }
}

// Fused GIN layer, R13: wave = 16-node tile (autonomous, no barrier).
// Gather: nodes processed sequentially; per node ALL 4 groups split its edge
// list (uniform trip = deg/4), idx for node k+1 prefetched during node k,
// shfl_xor(16,32) reduce, lanes 0-15 store row. Epilogue = R10 MFMA.
__global__ __launch_bounds__(256) void layer_kernel(
        const ushort_t* __restrict__ hin, ushort_t* __restrict__ hout,
        const int* __restrict__ offsets, const int* __restrict__ csr,
        const ushort_t* __restrict__ wt_hi, const ushort_t* __restrict__ wt_lo,
        const float* __restrict__ gin_b, const float* __restrict__ eps_arr,
        int layer, int N) {
    __shared__ float rows[4 * 16 * 64];   // 16KB: 4 waves x 16 nodes x 64 f32
    int t = threadIdx.x;
    int wv = t >> 6, lane = t & 63;
    int tile = blockIdx.x * 4 + wv;
    if (tile * 16 >= N) return;           // waves independent
    float* myrows = rows + wv * 16 * 64;
    float eps1 = 1.0f + eps_arr[layer];

    int g  = lane >> 4;    // edge group 0..3
    int sl = lane & 15;    // uint2 slot (dims 4sl..4sl+3)

    // one coalesced load covers all 17 offsets for this tile
    int off_l = offsets[min(tile * 16 + lane, N)];

    // prefetch node 0's indices
    int e0n = __shfl(off_l, 0, 64);
    int degn = __shfl(off_l, 1, 64) - e0n;
    int idxn = (lane < degn) ? csr[e0n + lane] : 0;

    for (int k = 0; k < 16; ++k) {
        int e0k = e0n, degk = degn, idxk = idxn;
        if (k < 15) {
            e0n = __shfl(off_l, k + 1, 64);
            degn = __shfl(off_l, k + 2, 64) - e0n;
            idxn = (lane < degn) ? csr[e0n + lane] : 0;
        }
        float ax = 0.f, ay = 0.f, az = 0.f, aw = 0.f;
        int dcap = min(degk, 64);
        #pragma unroll 8
        for (int j = g; j < dcap; j += 4) {
            int s = __shfl(idxk, j, 64);
            uint2 v = ((const uint2*)(hin + (size_t)s * 64))[sl];
            ax += h2f_lo(v.x); ay += h2f_hi(v.x);
            az += h2f_lo(v.y); aw += h2f_hi(v.y);
        }
        for (int j = 64 + g; j < degk; j += 4) {   // astronomically rare
            int s = csr[e0k + j];
            uint2 v = ((const uint2*)(hin + (size_t)s * 64))[sl];
            ax += h2f_lo(v.x); ay += h2f_hi(v.x);
            az += h2f_lo(v.y); aw += h2f_hi(v.y);
        }
        ax += __shfl_xor(ax, 16, 64); ax += __shfl_xor(ax, 32, 64);
        ay += __shfl_xor(ay, 16, 64); ay += __shfl_xor(ay, 32, 64);
        az += __shfl_xor(az, 16, 64); az += __shfl_xor(az, 32, 64);
        aw += __shfl_xor(aw, 16, 64); aw += __shfl_xor(aw, 32, 64);

        int node = tile * 16 + k;
        if (node < N) {
            uint2 self = ((const uint2*)(hin + (size_t)node * 64))[sl];
            ax = fmaf(eps1, h2f_lo(self.x), ax);
            ay = fmaf(eps1, h2f_hi(self.x), ay);
            az = fmaf(eps1, h2f_lo(self.y), az);
            aw = fmaf(eps1, h2f_hi(self.y), aw);
        }
        if (g == 0) {
            float4 r4; r4.x = ax; r4.y = ay; r4.z = az; r4.w = aw;
            *(float4*)&myrows[k * 64 + sl * 4] = r4;
        }
    }
    // intra-wave LDS ordering: compiler emits lgkmcnt before reads; no barrier.

    int c = lane & 15;     // node within tile / n-index
    int q = lane >> 4;     // quad
    int node16 = tile * 16 + c;

    const ushort_t* Whi = wt_hi + layer * 4096;
    const ushort_t* Wlo = wt_lo + layer * 4096;
    const float*    bl  = gin_b + layer * 64;

    v8bf bhi[2], blo2[2];
    #pragma unroll
    for (int kt = 0; kt < 2; ++kt) {
        float4 f0 = *(float4*)&myrows[c * 64 + kt * 32 + q * 8];
        float4 f1 = *(float4*)&myrows[c * 64 + kt * 32 + q * 8 + 4];
        float xs[8] = {f0.x, f0.y, f0.z, f0.w, f1.x, f1.y, f1.z, f1.w};
        #pragma unroll
        for (int j = 0; j < 8; ++j) {
            __bf16 h = (__bf16)xs[j];
            bhi[kt][j] = h;
            blo2[kt][j] = (__bf16)(xs[j] - (float)h);
        }
    }

    #pragma unroll
    for (int mt = 0; mt < 4; ++mt) {
        v4f acc = {0.f, 0.f, 0.f, 0.f};
        #pragma unroll
        for (int kt = 0; kt < 2; ++kt) {
            int dim = mt * 16 + c;
            size_t off = (size_t)dim * 64 + kt * 32 + q * 8;
            v8bf ah = __builtin_bit_cast(v8bf, *(const uint4*)(Whi + off));
            v8bf al = __builtin_bit_cast(v8bf, *(const uint4*)(Wlo + off));
            acc = __builtin_amdgcn_mfma_f32_16x16x32_bf16(ah, bhi[kt],  acc, 0, 0, 0);
            acc = __builtin_amdgcn_mfma_f32_16x16x32_bf16(ah, blo2[kt], acc, 0, 0, 0);
            acc = __builtin_amdgcn_mfma_f32_16x16x32_bf16(al, bhi[kt],  acc, 0, 0, 0);
        }
        float4 bv = ((const float4*)(bl + mt * 16))[q];
        float o0 = fmaxf(acc[0] + bv.x, 0.f);
        float o1 = fmaxf(acc[1] + bv.y, 0.f);
        float o2 = fmaxf(acc[2] + bv.z, 0.f);
        float o3 = fmaxf(acc[3] + bv.w, 0.f);
        uint2 pk;
        pk.x = f2h(o0) | (f2h(o1) << 16);
        pk.y = f2h(o2) | (f2h(o3) << 16);
        if (node16 < N)
            *(uint2*)(hout + (size_t)node16 * 64 + mt * 16 + q * 4) = pk;
    }
}

// Phase 1: dense partials, no atomics. gpart[(graph*SPLIT+sp)*192 + t].
__global__ __launch_bounds__(192) void readout_part_kernel(
        const ushort_t* __restrict__ H, const int* __restrict__ gids,
        float* __restrict__ gpart, int N) {
    int graph = blockIdx.x / SPLIT;
    int sp    = blockIdx.x % SPLIT;
    int lo = 0, hi = N;
    while (lo < hi) { int mid = (lo + hi) >> 1; if (gids[mid] < graph) lo = mid + 1; else hi = mid; }
    int start = lo;
    int lo2 = start, hi2 = N;
    while (lo2 < hi2) { int mid = (lo2 + hi2) >> 1; if (gids[mid] < graph + 1) lo2 = mid + 1; else hi2 = mid; }
    int end = lo2;
    int t = threadIdx.x;            // 0..191
    int l = t >> 6, d = t & 63;
    float acc = 0.0f;
    int cnt = end - start;
    if (cnt > 0) {
        int per = (cnt + SPLIT - 1) / SPLIT;
        int cs = start + sp * per;
        int ce = min(cs + per, end);
        const ushort_t* Hl = H + (size_t)l * N * 64;
        for (int n = cs; n < ce; ++n)
            acc += (float)__builtin_bit_cast(_Float16, Hl[(size_t)n * 64 + d]);
    }
    gpart[(size_t)(graph * SPLIT + sp) * 192 + t] = acc;   // unconditional
}

// Phase 2 fused with MLP: sum 16 partials -> gr, then 2-layer MLP.
__global__ __launch_bounds__(192) void mlp_kernel(
        const float* __restrict__ gpart,
        const float* __restrict__ W1, const float* __restrict__ b1,
        const float* __restrict__ W2, const float* __restrict__ b2,
        float* __restrict__ out) {
    __shared__ float gr[192];
    __shared__ float hid[128];
    int graph = blockIdx.x;
    int t = threadIdx.x;
    float a = 0.f;
    #pragma unroll
    for (int sp = 0; sp < SPLIT; ++sp)
        a += gpart[(size_t)(graph * SPLIT + sp) * 192 + t];
    gr[t] = a;
    __syncthreads();
    if (t < 128) {
        float s = b1[t];
        for (int k = 0; k < 192; ++k) s = fmaf(gr[k], W1[k * 128 + t], s);
        hid[t] = fmaxf(s, 0.0f);
    }
    __syncthreads();
    if (t < 32) {
        float s = b2[t];
        for (int k = 0; k < 128; ++k) s = fmaf(hid[k], W2[k * 32 + t], s);
        out[graph * 32 + t] = s;
    }
}

extern "C" void kernel_launch(void* const* d_in, const int* in_sizes, int n_in,
                              void* d_out, int out_size, void* d_ws, size_t ws_size,
                              hipStream_t stream) {
    const float* x     = (const float*)d_in[0];
    const float* gin_W = (const float*)d_in[1];
    const float* gin_b = (const float*)d_in[2];
    const float* eps   = (const float*)d_in[3];
    const float* r_W1  = (const float*)d_in[4];
    const float* r_b1  = (const float*)d_in[5];
    const float* r_W2  = (const float*)d_in[6];
    const float* r_b2  = (const float*)d_in[7];
    const int*   src   = (const int*)d_in[8];
    const int*   dst   = (const int*)d_in[9];
    const int*   gids  = (const int*)d_in[10];

    int N = in_sizes[0] / 64;       // 100000
    int E = in_sizes[8];            // 1200000
    int B = out_size / 32;          // 256

    int nbkt = (N + BS - 1) / BS;   // 196 (<= 256)
    int ebpb = (E + NBLK - 1) / NBLK;
    int n4 = N * 64 / 4;
    int castBlocks = (n4 + 255) / 256;
    int wtotal = 3 * 4096;
    int prepBlocks = (wtotal + 255) / 256;

    // workspace layout (4B words), all regions fully written before read:
    //   gpart[B*SPLIT*192]
    //   cnt2d[NBLK*nbkt] | blkoff[nbkt*NBLK] | btot[nbkt] | bbase[nbkt+1]
    //   offsets[N+1] | bkt[E] | csr[E] | pad
    //   xh[N*64 f16] | H[3*N*64 f16] | whi[3*4096] | wlo[3*4096]
    int* ws       = (int*)d_ws;
    float* gpart  = (float*)ws;
    int* cnt2d    = ws + (size_t)B * SPLIT * 192;
    int* blkoff   = cnt2d + (size_t)NBLK * nbkt;
    int* btot     = blkoff + (size_t)nbkt * NBLK;
    int* bbase    = btot + nbkt;
    int* offsets  = bbase + (nbkt + 1);
    unsigned int* bkt = (unsigned int*)(offsets + (N + 1));
    int* csr      = (int*)(bkt + E);
    size_t w      = (size_t)(csr + E - ws);
    w = (w + 15) & ~(size_t)15;     // 64B align
    ushort_t* xh  = (ushort_t*)(ws + w);
    ushort_t* H   = xh + (size_t)N * 64;
    ushort_t* whi = H + 3 * (size_t)N * 64;
    ushort_t* wlo = whi + 3 * 4096;

    pre_kernel<<<NBLK + castBlocks + prepBlocks, 256, 0, stream>>>(
        dst, cnt2d, E, nbkt, ebpb, x, xh, n4, castBlocks, gin_W, whi, wlo, wtotal);
    colscan_kernel<<<nbkt, 256, 0, stream>>>(cnt2d, blkoff, btot, nbkt);
    bucket_base_kernel<<<1, 256, 0, stream>>>(btot, bbase, offsets, nbkt, N, E);
    bucket_scatter_kernel<<<NBLK, 256, 0, stream>>>(src, dst, bbase, blkoff, bkt, E, nbkt, ebpb);
    csr_build_kernel<<<nbkt, 256, 0, stream>>>(bkt, bbase, offsets, csr, N, nbkt);

    int lbk = (N + 63) / 64;        // 4 tiles (waves) of 16 nodes per block
    ushort_t* H0 = H;
    ushort_t* H1 = H + (size_t)N * 64;
    ushort_t* H2 = H + 2 * (size_t)N * 64;

    layer_kernel<<<lbk, 256, 0, stream>>>(xh, H0, offsets, csr, whi, wlo, gin_b, eps, 0, N);
    layer_kernel<<<lbk, 256, 0, stream>>>(H0, H1, offsets, csr, whi, wlo, gin_b, eps, 1, N);
    layer_kernel<<<lbk, 256, 0, stream>>>(H1, H2, offsets, csr, whi, wlo, gin_b, eps, 2, N);

    readout_part_kernel<<<B * SPLIT, 192, 0, stream>>>(H, gids, gpart, N);
    mlp_kernel<<<B, 192, 0, stream>>>(gpart, r_W1, r_b1, r_W2, r_b2, (float*)d_out);
}